// Round 1
// baseline (1475.670 us; speedup 1.0000x reference)
//
#include <hip/hip_runtime.h>
#include <hip/hip_bf16.h>

#define T_TASKS 4
#define E_SPEC  4
#define E_SH    4
#define D_DIM   1024
#define H_DIM   2048
#define B_DIM   4096
#define NSLOT   20
#define GRP     4

typedef __bf16 bf16x8 __attribute__((ext_vector_type(8)));
typedef float  f32x4  __attribute__((ext_vector_type(4)));
typedef unsigned short ushort_t;
typedef unsigned short ushort8_t __attribute__((ext_vector_type(8)));

__device__ __forceinline__ unsigned short f32_to_bf16(float f){
  union { float f; unsigned int u; } v; v.f = f;
  unsigned int u = v.u;
  unsigned int r = (u + 0x7fffu + ((u >> 16) & 1u)) >> 16;
  return (unsigned short)r;
}
__device__ __forceinline__ float bf16_to_f32(unsigned short h){
  union { unsigned int u; float f; } v; v.u = ((unsigned int)h) << 16;
  return v.f;
}
__device__ __forceinline__ void gload_lds16(const void* g, void* l){
  __builtin_amdgcn_global_load_lds(
      (const __attribute__((address_space(1))) void*)g,
      (__attribute__((address_space(3))) void*)l, 16, 0, 0);
}

// ---------------- elementwise f32 -> bf16 cast ----------------
__global__ __launch_bounds__(256)
void cast_f32_bf16(const float* __restrict__ in, ushort_t* __restrict__ out, int n){
  const int i = (blockIdx.x * 256 + threadIdx.x) * 4;
  if (i < n){
    const float4 v = *reinterpret_cast<const float4*>(in + i);
    ushort4 o;
    o.x = f32_to_bf16(v.x); o.y = f32_to_bf16(v.y);
    o.z = f32_to_bf16(v.z); o.w = f32_to_bf16(v.w);
    *reinterpret_cast<ushort4*>(out + i) = o;
  }
}

// ---------------- tiled transpose + cast: in[R][C] f32 -> out[C][R] bf16 ----------------
__global__ __launch_bounds__(256)
void transpose_cast(const float* __restrict__ in, ushort_t* __restrict__ out, int R, int C){
  __shared__ float tile[32][33];
  const int c0 = blockIdx.x * 32, r0 = blockIdx.y * 32;
  const float* ip = in  + (size_t)blockIdx.z * R * C;
  ushort_t*    op = out + (size_t)blockIdx.z * R * C;
  const int tx = threadIdx.x, ty = threadIdx.y;   // block (32, 8)
  #pragma unroll
  for (int j = 0; j < 32; j += 8)
    tile[ty + j][tx] = ip[(size_t)(r0 + ty + j) * C + c0 + tx];
  __syncthreads();
  #pragma unroll
  for (int j = 0; j < 32; j += 8)
    op[(size_t)(c0 + ty + j) * R + r0 + tx] = f32_to_bf16(tile[tx][ty + j]);
}

// ---------------- expert FFN GEMM: C = act(A @ W + b) ----------------
// A: [M,K] bf16 row-major; Bt: W^T [N,K] bf16 row-major; out bf16.
// LAYER 1: X from shb (shared slots) / trb (task slots), relu, out = hbuf[group-local]
// LAYER 2: X = hbuf[group-local], no relu, out = eout[slot-global]
template<int LAYER>
__global__ __launch_bounds__(256, 2)
void ffn_gemm(const ushort_t* __restrict__ Xbase,
              const ushort_t* __restrict__ shb,
              const ushort_t* __restrict__ Bt,
              const float* __restrict__ shr_b,
              const float* __restrict__ spec_b,
              ushort_t* __restrict__ outp,
              int z0)
{
  constexpr int M = B_DIM;
  constexpr int N = (LAYER == 1) ? H_DIM : D_DIM;
  constexpr int K = (LAYER == 1) ? D_DIM : H_DIM;
  constexpr int BM = 128, BN = 128, BK = 32;

  const int slot = z0 + blockIdx.z;
  const ushort_t* X;
  const float* bias;
  if (LAYER == 1){
    if (slot < E_SH){ X = shb; bias = shr_b + (size_t)slot * N; }
    else { X = Xbase + (size_t)((slot - E_SH) >> 2) * M * K; bias = spec_b + (size_t)(slot - E_SH) * N; }
  } else {
    X = Xbase + (size_t)blockIdx.z * M * K;
    bias = (slot < E_SH) ? (shr_b + (size_t)slot * N) : (spec_b + (size_t)(slot - E_SH) * N);
  }
  ushort_t* Cout = (LAYER == 1) ? (outp + (size_t)blockIdx.z * M * N)
                                : (outp + (size_t)slot * M * N);

  const int row0 = blockIdx.y * BM;
  const int col0 = blockIdx.x * BN;

  __shared__ __align__(16) ushort_t As[BM * BK];
  __shared__ __align__(16) ushort_t Bs[BN * BK];

  const int tid  = threadIdx.x;
  const int lane = tid & 63;
  const int wave = tid >> 6;
  const int wr = wave >> 1, wc = wave & 1;

  f32x4 acc[4][4] = {};

  const ushort_t* Ag = X + (size_t)row0 * K;
  const ushort_t* Bg = Bt + (size_t)slot * N * K + (size_t)col0 * K;

  const int sm  = tid >> 2;        // 0..63 (row within half tile)
  const int ske = (tid & 3) * 8;   // k-element offset of this 16B chunk

  for (int k0 = 0; k0 < K; k0 += BK){
    gload_lds16(Ag + (size_t)sm * K        + k0 + ske, (char*)As + tid * 16);
    gload_lds16(Ag + (size_t)(sm + 64) * K + k0 + ske, (char*)As + tid * 16 + 4096);
    gload_lds16(Bg + (size_t)sm * K        + k0 + ske, (char*)Bs + tid * 16);
    gload_lds16(Bg + (size_t)(sm + 64) * K + k0 + ske, (char*)Bs + tid * 16 + 4096);
    __syncthreads();

    bf16x8 af[4], bfv[4];
    const int kr = (lane >> 4) * 8;
    const int rl = lane & 15;
    #pragma unroll
    for (int i = 0; i < 4; i++){
      af[i]  = *reinterpret_cast<const bf16x8*>(&As[(wr * 64 + i * 16 + rl) * BK + kr]);
      bfv[i] = *reinterpret_cast<const bf16x8*>(&Bs[(wc * 64 + i * 16 + rl) * BK + kr]);
    }
    #pragma unroll
    for (int i = 0; i < 4; i++)
      #pragma unroll
      for (int j = 0; j < 4; j++)
        acc[i][j] = __builtin_amdgcn_mfma_f32_16x16x32_bf16(af[i], bfv[j], acc[i][j], 0, 0, 0);
    __syncthreads();
  }

  const int rl = lane & 15;
  const int rq = lane >> 4;
  #pragma unroll
  for (int i = 0; i < 4; i++){
    #pragma unroll
    for (int j = 0; j < 4; j++){
      const int col = col0 + wc * 64 + j * 16 + rl;
      const float bv = bias[col];
      #pragma unroll
      for (int r = 0; r < 4; r++){
        const int row = row0 + wr * 64 + i * 16 + rq * 4 + r;
        float v = acc[i][j][r] + bv;
        if (LAYER == 1) v = v > 0.f ? v : 0.f;
        Cout[(size_t)row * N + col] = f32_to_bf16(v);
      }
    }
  }
}

// ---------------- gate logits + softmax (fp32, one wave per row) ----------------
template<int NG>
__global__ __launch_bounds__(256)
void gate_softmax(const float* __restrict__ X, const float* __restrict__ W,
                  const float* __restrict__ b, float* __restrict__ out){
  const int lane = threadIdx.x & 63;
  const int wave = threadIdx.x >> 6;
  const int row  = blockIdx.x * 4 + wave;
  const float* x = X + (size_t)row * D_DIM;
  float a[NG];
  #pragma unroll
  for (int e = 0; e < NG; e++) a[e] = 0.f;
  for (int d = lane; d < D_DIM; d += 64){
    const float xv = x[d];
    #pragma unroll
    for (int e = 0; e < NG; e++) a[e] += xv * W[(size_t)d * NG + e];
  }
  #pragma unroll
  for (int e = 0; e < NG; e++){
    float v = a[e];
    #pragma unroll
    for (int off = 32; off > 0; off >>= 1) v += __shfl_down(v, off, 64);
    a[e] = v;
  }
  if (lane == 0){
    float m = -1e30f;
    #pragma unroll
    for (int e = 0; e < NG; e++){ a[e] += b[e]; m = fmaxf(m, a[e]); }
    float s = 0.f;
    #pragma unroll
    for (int e = 0; e < NG; e++){ a[e] = expf(a[e] - m); s += a[e]; }
    const float inv = 1.f / s;
    #pragma unroll
    for (int e = 0; e < NG; e++) out[(size_t)row * NG + e] = a[e] * inv;
  }
}

// ---------------- gated combine ----------------
__global__ __launch_bounds__(256)
void combine_kernel(const ushort_t* __restrict__ eout,  // [20][B][D] bf16 (shared 0..3, then t-major spec)
                    const float* __restrict__ gw,       // [T][B][8]
                    const float* __restrict__ sgw,      // [B][20]
                    float* __restrict__ out)            // [T][B][D] then [B][D] f32
{
  const int gidx = blockIdx.x * 256 + threadIdx.x;
  const int b  = gidx >> 7;            // D/8 = 128 chunks per row
  const int dc = (gidx & 127) << 3;
  float accT[T_TASKS][8];
  float accS[8];
  #pragma unroll
  for (int t = 0; t < T_TASKS; t++)
    #pragma unroll
    for (int j = 0; j < 8; j++) accT[t][j] = 0.f;
  #pragma unroll
  for (int j = 0; j < 8; j++) accS[j] = 0.f;

  const size_t bd = (size_t)b * D_DIM + dc;
  #pragma unroll
  for (int s = 0; s < NSLOT; s++){
    ushort8_t uv = *reinterpret_cast<const ushort8_t*>(eout + (size_t)s * B_DIM * D_DIM + bd);
    float v[8];
    #pragma unroll
    for (int j = 0; j < 8; j++) v[j] = bf16_to_f32(uv[j]);
    const float wsh = sgw[(size_t)b * NSLOT + s];
    #pragma unroll
    for (int j = 0; j < 8; j++) accS[j] += wsh * v[j];
    if (s < E_SH){
      #pragma unroll
      for (int t = 0; t < T_TASKS; t++){
        const float w = gw[((size_t)t * B_DIM + b) * 8 + s];
        #pragma unroll
        for (int j = 0; j < 8; j++) accT[t][j] += w * v[j];
      }
    } else {
      const int t = (s - E_SH) >> 2, es = (s - E_SH) & 3;
      const float w = gw[((size_t)t * B_DIM + b) * 8 + 4 + es];
      #pragma unroll
      for (int j = 0; j < 8; j++) accT[t][j] += w * v[j];
    }
  }
  #pragma unroll
  for (int t = 0; t < T_TASKS; t++)
    #pragma unroll
    for (int j = 0; j < 8; j++)
      out[(size_t)t * B_DIM * D_DIM + bd + j] = accT[t][j];
  #pragma unroll
  for (int j = 0; j < 8; j++)
    out[(size_t)T_TASKS * B_DIM * D_DIM + bd + j] = accS[j];
}

extern "C" void kernel_launch(void* const* d_in, const int* in_sizes, int n_in,
                              void* d_out, int out_size, void* d_ws, size_t ws_size,
                              hipStream_t stream){
  const float* task_reps  = (const float*)d_in[0];
  const float* shared_rep = (const float*)d_in[1];
  const float* spec_w1 = (const float*)d_in[2];
  const float* spec_b1 = (const float*)d_in[3];
  const float* spec_w2 = (const float*)d_in[4];
  const float* spec_b2 = (const float*)d_in[5];
  const float* shr_w1  = (const float*)d_in[6];
  const float* shr_b1  = (const float*)d_in[7];
  const float* shr_w2  = (const float*)d_in[8];
  const float* shr_b2  = (const float*)d_in[9];
  const float* gate_w  = (const float*)d_in[10];
  const float* gate_b  = (const float*)d_in[11];
  const float* sgate_w = (const float*)d_in[12];
  const float* sgate_b = (const float*)d_in[13];

  char* ws = (char*)d_ws;
  size_t off = 0;
  auto carve = [&](size_t bytes) -> void* {
    void* p = ws + off; off += (bytes + 255) & ~(size_t)255; return p;
  };
  ushort_t* trb  = (ushort_t*)carve((size_t)T_TASKS * B_DIM * D_DIM * 2);
  ushort_t* shb  = (ushort_t*)carve((size_t)B_DIM * D_DIM * 2);
  ushort_t* w1t  = (ushort_t*)carve((size_t)NSLOT * H_DIM * D_DIM * 2);   // [20][H][D]
  ushort_t* w2t  = (ushort_t*)carve((size_t)NSLOT * D_DIM * H_DIM * 2);   // [20][D][H]
  ushort_t* hbuf = (ushort_t*)carve((size_t)GRP * B_DIM * H_DIM * 2);     // [GRP][B][H]
  ushort_t* eout = (ushort_t*)carve((size_t)NSLOT * B_DIM * D_DIM * 2);   // [20][B][D]
  float*    gwb  = (float*)carve((size_t)T_TASKS * B_DIM * 8 * 4);
  float*    sgwb = (float*)carve((size_t)B_DIM * NSLOT * 4);

  // activation casts
  {
    const int n = T_TASKS * B_DIM * D_DIM;
    cast_f32_bf16<<<dim3(n / 4 / 256), dim3(256), 0, stream>>>(task_reps, trb, n);
    const int n2 = B_DIM * D_DIM;
    cast_f32_bf16<<<dim3(n2 / 4 / 256), dim3(256), 0, stream>>>(shared_rep, shb, n2);
  }
  // weight transposes: w1 slabs [D,H] -> [H,D]; w2 slabs [H,D] -> [D,H]
  transpose_cast<<<dim3(H_DIM/32, D_DIM/32, E_SH), dim3(32,8), 0, stream>>>(shr_w1, w1t, D_DIM, H_DIM);
  transpose_cast<<<dim3(H_DIM/32, D_DIM/32, 16),  dim3(32,8), 0, stream>>>(spec_w1, w1t + (size_t)E_SH*H_DIM*D_DIM, D_DIM, H_DIM);
  transpose_cast<<<dim3(D_DIM/32, H_DIM/32, E_SH), dim3(32,8), 0, stream>>>(shr_w2, w2t, H_DIM, D_DIM);
  transpose_cast<<<dim3(D_DIM/32, H_DIM/32, 16),  dim3(32,8), 0, stream>>>(spec_w2, w2t + (size_t)E_SH*D_DIM*H_DIM, H_DIM, D_DIM);

  // gates (fp32, independent of GEMM chain)
  for (int t = 0; t < T_TASKS; t++)
    gate_softmax<8><<<dim3(B_DIM/4), dim3(256), 0, stream>>>(
        task_reps + (size_t)t * B_DIM * D_DIM, gate_w + (size_t)t * D_DIM * 8,
        gate_b + (size_t)t * 8, gwb + (size_t)t * B_DIM * 8);
  gate_softmax<20><<<dim3(B_DIM/4), dim3(256), 0, stream>>>(shared_rep, sgate_w, sgate_b, sgwb);

  // expert FFNs in groups of GRP slots
  for (int g = 0; g < NSLOT / GRP; ++g){
    ffn_gemm<1><<<dim3(H_DIM/128, B_DIM/128, GRP), dim3(256), 0, stream>>>(
        trb, shb, w1t, shr_b1, spec_b1, hbuf, g * GRP);
    ffn_gemm<2><<<dim3(D_DIM/128, B_DIM/128, GRP), dim3(256), 0, stream>>>(
        hbuf, hbuf, w2t, shr_b2, spec_b2, eout, g * GRP);
  }

  combine_kernel<<<dim3(B_DIM * (D_DIM/8) / 256), dim3(256), 0, stream>>>(eout, gwb, sgwb, (float*)d_out);
}